// Round 9
// baseline (861.505 us; speedup 1.0000x reference)
//
#include <hip/hip_runtime.h>
#include <hip/hip_cooperative_groups.h>

namespace cg = cooperative_groups;

#define N 6144
#define E 196608
#define EN (E + N)      // 202752
#define LGAT 10
#define LOG2E 1.4426950408889634f
#define MCH 192   // 6144/32

typedef unsigned int u32;

// order-preserving float<->uint for atomicMax/Min on floats (incl. negatives)
__device__ __forceinline__ u32 f2key(float f) {
    u32 u = __float_as_uint(f);
    return (u & 0x80000000u) ? ~u : (u | 0x80000000u);
}
__device__ __forceinline__ float key2f(u32 k) {
    u32 u = (k & 0x80000000u) ? (k & 0x7FFFFFFFu) : ~k;
    return __uint_as_float(u);
}

struct P {
    // fp32 inputs
    const float *x, *mask, *gat_W, *gat_asrc, *gat_adst, *gat_b;
    const float *in_w, *in_b, *out_w, *out_b;
    const float *Wq, *bq, *Wk, *bk, *Wv, *bv, *Wsk, *bsk;
    const float *W1, *b1, *W2, *b2, *W3, *b3, *cW, *cb;
    const int *src, *dst;
    // fp32 workspace
    float4 *nodeA, *nodeB;          // per-node {xp0,xp1,xp2,ssrc*log2e}
    float *sdstA, *sdstB;           // sdst*log2e
    float *q3, *q2, *h2, *h3, *part;
    float4 *kvpack4;                // per-node {k0,k1,k2,v0},{v1,v2,0,0}
    float4 *kv2;                    // per-node {k0,k1,k2,v0},{v1,v2,0,0} (TC)
    float *a1pre, *a2buf, *sumres;
    u32 *deg, *offs, *cursor, *kmaxk, *kmink;
    int *ssorted;
    float *out;
};

// ===========================================================================
// Mega kernel: all phases grid-stride; valid for any grid with >=72 blocks.
// ===========================================================================
__global__ void __launch_bounds__(256, 2) k_mega(P p) {
    cg::grid_group grid = cg::this_grid();
    const int b = blockIdx.x;
    const int tid = threadIdx.x;
    const int gid = b * 256 + tid;
    const int NB = gridDim.x;
    const int NT = NB * 256;
    const int NG = NT >> 5;          // 32-lane groups
    const int lane = gid & 31;
    const int g0 = gid >> 5;

    __shared__ u32 spart[256];
    __shared__ float4 kv4[MCH * 2];   // 6 KB
    __shared__ float red[64];
    __shared__ float a1s[16];
    __shared__ float a2s[32];

    // ---- phase 0: init deg + small accumulators ----
    for (int t = gid; t < N; t += NT) p.deg[t] = 0u;
    if (gid < 3) p.kmaxk[gid] = 0u;
    else if (gid < 6) p.kmink[gid - 3] = 0xFFFFFFFFu;
    else if (gid < 22) p.a1pre[gid - 6] = 0.f;
    else if (gid == 22) p.sumres[0] = 0.f;
    grid.sync();

    // ---- phase 1: layer-0 node transform + dst histogram ----
    for (int n = gid; n < N; n += NT) {
        float h0 = p.x[n * 3 + 0], h1 = p.x[n * 3 + 1], h2 = p.x[n * 3 + 2];
        const float* W = p.gat_W;
        float xp0 = h0 * W[0] + h1 * W[3] + h2 * W[6];
        float xp1 = h0 * W[1] + h1 * W[4] + h2 * W[7];
        float xp2 = h0 * W[2] + h1 * W[5] + h2 * W[8];
        float ss = LOG2E * (xp0 * p.gat_asrc[0] + xp1 * p.gat_asrc[1] + xp2 * p.gat_asrc[2]);
        p.nodeA[n] = make_float4(xp0, xp1, xp2, ss);
        p.sdstA[n] = LOG2E * (xp0 * p.gat_adst[0] + xp1 * p.gat_adst[1] + xp2 * p.gat_adst[2]);
    }
    for (int e = gid; e < EN; e += NT) {
        int d = (e < E) ? p.dst[e] : (e - E);
        atomicAdd(&p.deg[d], 1u);
    }
    grid.sync();

    // ---- phase 2: exclusive scan (block 0) ----
    if (b == 0) {
        int t = tid;
        u32 loc[24];
        u32 sum = 0;
        #pragma unroll
        for (int i = 0; i < 24; ++i) { loc[i] = sum; sum += p.deg[t * 24 + i]; }
        spart[t] = sum;
        __syncthreads();
        for (int o = 1; o < 256; o <<= 1) {
            u32 v = (t >= o) ? spart[t - o] : 0u;
            __syncthreads();
            spart[t] += v;
            __syncthreads();
        }
        u32 base = (t == 0) ? 0u : spart[t - 1];
        #pragma unroll
        for (int i = 0; i < 24; ++i) {
            u32 off = base + loc[i];
            p.offs[t * 24 + i] = off;
            p.cursor[t * 24 + i] = off;
        }
        if (t == 255) p.offs[N] = spart[255];
    }
    grid.sync();

    // ---- phase 3: scatter src ids into dst-sorted order ----
    for (int e = gid; e < EN; e += NT) {
        int s = (e < E) ? p.src[e] : (e - E);
        int d = (e < E) ? p.dst[e] : (e - E);
        u32 pos = atomicAdd(&p.cursor[d], 1u);
        p.ssorted[pos] = s;
    }
    grid.sync();

    // ---- phase 4: 10 GAT layers (32 lanes/dst, single gather) ----
    float4* nin = p.nodeA;  float* sdin = p.sdstA;
    float4* nout = p.nodeB; float* sdout = p.sdstB;
    for (int l = 0; l < LGAT; ++l) {
        for (int d = g0; d < N; d += NG) {
            u32 beg = p.offs[d], end = p.offs[d + 1];
            float sd = sdin[d];
            u32 i0 = beg + lane, i1 = i0 + 32, i2 = i0 + 64, i3 = i0 + 96;
            bool e0 = i0 < end, e1 = i1 < end, e2 = i2 < end, e3 = i3 < end;
            int j0 = e0 ? p.ssorted[i0] : 0;
            int j1 = e1 ? p.ssorted[i1] : 0;
            int j2 = e2 ? p.ssorted[i2] : 0;
            int j3 = e3 ? p.ssorted[i3] : 0;
            float4 r0 = nin[j0], r1 = nin[j1], r2 = nin[j2], r3 = nin[j3];
            float v0 = r0.w + sd; v0 = (v0 >= 0.f) ? v0 : 0.2f * v0; v0 = e0 ? v0 : -1e30f;
            float v1 = r1.w + sd; v1 = (v1 >= 0.f) ? v1 : 0.2f * v1; v1 = e1 ? v1 : -1e30f;
            float v2 = r2.w + sd; v2 = (v2 >= 0.f) ? v2 : 0.2f * v2; v2 = e2 ? v2 : -1e30f;
            float v3 = r3.w + sd; v3 = (v3 >= 0.f) ? v3 : 0.2f * v3; v3 = e3 ? v3 : -1e30f;
            float mx = fmaxf(fmaxf(v0, v1), fmaxf(v2, v3));
            for (u32 i = i0 + 128; i < end; i += 32) {
                float4 r = nin[p.ssorted[i]];
                float v = r.w + sd; v = (v >= 0.f) ? v : 0.2f * v;
                mx = fmaxf(mx, v);
            }
            #pragma unroll
            for (int o = 1; o < 32; o <<= 1) mx = fmaxf(mx, __shfl_xor(mx, o));
            float w0 = exp2f(v0 - mx), w1 = exp2f(v1 - mx),
                  w2 = exp2f(v2 - mx), w3 = exp2f(v3 - mx);
            float sz = w0 + w1 + w2 + w3;
            float s0 = w0 * r0.x + w1 * r1.x + w2 * r2.x + w3 * r3.x;
            float s1 = w0 * r0.y + w1 * r1.y + w2 * r2.y + w3 * r3.y;
            float s2 = w0 * r0.z + w1 * r1.z + w2 * r2.z + w3 * r3.z;
            for (u32 i = i0 + 128; i < end; i += 32) {
                float4 r = nin[p.ssorted[i]];
                float v = r.w + sd; v = (v >= 0.f) ? v : 0.2f * v;
                float w = exp2f(v - mx);
                sz += w; s0 += w * r.x; s1 += w * r.y; s2 += w * r.z;
            }
            #pragma unroll
            for (int o = 1; o < 32; o <<= 1) {
                sz += __shfl_xor(sz, o);
                s0 += __shfl_xor(s0, o);
                s1 += __shfl_xor(s1, o);
                s2 += __shfl_xor(s2, o);
            }
            if (lane == 0) {
                float z = sz + 1e-16f;
                float o0 = s0 / z + p.gat_b[l * 3 + 0];
                float o1 = s1 / z + p.gat_b[l * 3 + 1];
                float o2 = s2 / z + p.gat_b[l * 3 + 2];
                if (l < LGAT - 1) {
                    o0 = fmaxf(o0, 0.f); o1 = fmaxf(o1, 0.f); o2 = fmaxf(o2, 0.f);
                    const float* W = p.gat_W + (l + 1) * 9;
                    float xp0 = o0 * W[0] + o1 * W[3] + o2 * W[6];
                    float xp1 = o0 * W[1] + o1 * W[4] + o2 * W[7];
                    float xp2 = o0 * W[2] + o1 * W[5] + o2 * W[8];
                    const float* as = p.gat_asrc + (l + 1) * 3;
                    const float* ad = p.gat_adst + (l + 1) * 3;
                    float ss = LOG2E * (xp0 * as[0] + xp1 * as[1] + xp2 * as[2]);
                    nout[d] = make_float4(xp0, xp1, xp2, ss);
                    sdout[d] = LOG2E * (xp0 * ad[0] + xp1 * ad[1] + xp2 * ad[2]);
                } else {
                    float pr[9];
                    #pragma unroll
                    for (int j = 0; j < 9; ++j)
                        pr[j] = o0 * p.in_w[j * 3 + 0] + o1 * p.in_w[j * 3 + 1] +
                                o2 * p.in_w[j * 3 + 2] + p.in_b[j];
                    p.q3[d * 3 + 0] = pr[0]; p.q3[d * 3 + 1] = pr[1]; p.q3[d * 3 + 2] = pr[2];
                    p.kvpack4[d * 2 + 0] = make_float4(pr[3], pr[4], pr[5], pr[6]);
                    p.kvpack4[d * 2 + 1] = make_float4(pr[7], pr[8], 0.f, 0.f);
                }
            }
        }
        grid.sync();
        float4* tn = nin; nin = nout; nout = tn;
        float* ts = sdin; sdin = sdout; sdout = ts;
    }

    // ---- phase 5: global k min/max per head (blocks 0..23 fully active) ---
    if (gid < N) {
        float4 a = p.kvpack4[gid * 2];
        float kk[3] = {a.x, a.y, a.z};
        #pragma unroll
        for (int hh = 0; hh < 3; ++hh) {
            float mx = kk[hh], mn = kk[hh];
            #pragma unroll
            for (int o = 32; o; o >>= 1) {
                mx = fmaxf(mx, __shfl_xor(mx, o));
                mn = fminf(mn, __shfl_xor(mn, o));
            }
            if ((tid & 63) == 0) {
                atomicMax(&p.kmaxk[hh], f2key(mx));
                atomicMin(&p.kmink[hh], f2key(mn));
            }
        }
    }
    grid.sync();

    // ---- phase 6: MHA partial over 768 virtual blocks (24 ntiles x 32 ch) -
    for (int vb = b; vb < 768; vb += NB) {
        int chunk = vb & 31;
        int ntile = vb >> 5;
        __syncthreads();     // guard kv4 reuse across iterations
        for (int i = tid; i < MCH * 2; i += 256) kv4[i] = p.kvpack4[chunk * MCH * 2 + i];
        __syncthreads();
        int n = ntile * 256 + tid;
        float q0 = p.q3[n * 3 + 0], q1 = p.q3[n * 3 + 1], q2 = p.q3[n * 3 + 2];
        float kmx0 = key2f(p.kmaxk[0]), kmx1 = key2f(p.kmaxk[1]), kmx2 = key2f(p.kmaxk[2]);
        float kmn0 = key2f(p.kmink[0]), kmn1 = key2f(p.kmink[1]), kmn2 = key2f(p.kmink[2]);
        float q0s = q0 * LOG2E, q1s = q1 * LOG2E, q2s = q2 * LOG2E;
        float nM0 = -((q0 >= 0.f) ? q0s * kmx0 : q0s * kmn0);
        float nM1 = -((q1 >= 0.f) ? q1s * kmx1 : q1s * kmn1);
        float nM2 = -((q2 >= 0.f) ? q2s * kmx2 : q2s * kmn2);
        float num0 = 0, den0 = 0, num1 = 0, den1 = 0, num2 = 0, den2 = 0;
        #pragma unroll 2
        for (int mm = 0; mm < MCH; ++mm) {
            float4 a = kv4[mm * 2], bb = kv4[mm * 2 + 1];
            float t0 = exp2f(fmaf(q0s, a.x, nM0)); den0 += t0; num0 = fmaf(t0, a.w, num0);
            float t1 = exp2f(fmaf(q1s, a.y, nM1)); den1 += t1; num1 = fmaf(t1, bb.x, num1);
            float t2 = exp2f(fmaf(q2s, a.z, nM2)); den2 += t2; num2 = fmaf(t2, bb.y, num2);
        }
        float* pp = p.part + (size_t)chunk * 6 * N + n;
        pp[0] = num0; pp[N] = den0; pp[2 * N] = num1;
        pp[3 * N] = den1; pp[4 * N] = num2; pp[5 * N] = den2;
    }
    grid.sync();

    // ---- phase 7: MHA reduce + out-proj + TC records ----
    if (gid < N) {
        int n = gid;
        float num[3] = {0.f, 0.f, 0.f}, den[3] = {0.f, 0.f, 0.f};
        for (int c = 0; c < 32; ++c) {
            const float* pp = p.part + (size_t)c * 6 * N + n;
            #pragma unroll
            for (int hh = 0; hh < 3; ++hh) {
                num[hh] += pp[hh * 2 * N];
                den[hh] += pp[(hh * 2 + 1) * N];
            }
        }
        float o[3];
        #pragma unroll
        for (int hh = 0; hh < 3; ++hh) o[hh] = num[hh] / den[hh];
        float h2v[3];
        #pragma unroll
        for (int c = 0; c < 3; ++c) {
            h2v[c] = p.out_b[c] + o[0] * p.out_w[c * 3 + 0] +
                     o[1] * p.out_w[c * 3 + 1] + o[2] * p.out_w[c * 3 + 2];
            p.h2[n * 3 + c] = h2v[c];
        }
        float q2v[3], k2v[3], v2v[3];
        #pragma unroll
        for (int c = 0; c < 3; ++c) {
            q2v[c] = p.bq[c] + h2v[0] * p.Wq[c] + h2v[1] * p.Wq[3 + c] + h2v[2] * p.Wq[6 + c];
            k2v[c] = p.bk[c] + h2v[0] * p.Wk[c] + h2v[1] * p.Wk[3 + c] + h2v[2] * p.Wk[6 + c];
            v2v[c] = p.bv[c] + h2v[0] * p.Wv[c] + h2v[1] * p.Wv[3 + c] + h2v[2] * p.Wv[6 + c];
            p.q2[n * 3 + c] = q2v[c];
        }
        p.kv2[n * 2 + 0] = make_float4(k2v[0], k2v[1], k2v[2], v2v[0]);
        p.kv2[n * 2 + 1] = make_float4(v2v[1], v2v[2], 0.f, 0.f);
    }
    grid.sync();

    // ---- phase 8: TC edge (32 lanes/dst, single gather) ----
    for (int d = g0; d < N; d += NG) {
        u32 beg = p.offs[d], end = p.offs[d + 1];
        float q0 = p.q2[d * 3 + 0], q1 = p.q2[d * 3 + 1], q2 = p.q2[d * 3 + 2];
        const float RS3L = 0.57735026919f * LOG2E;
        u32 i0 = beg + lane, i1 = i0 + 32;
        bool e0 = i0 < end, e1 = i1 < end;
        int j0 = e0 ? p.ssorted[i0] : 0;
        int j1 = e1 ? p.ssorted[i1] : 0;
        float4 ka0 = p.kv2[j0 * 2], kb0 = p.kv2[j0 * 2 + 1];
        float4 ka1 = p.kv2[j1 * 2], kb1 = p.kv2[j1 * 2 + 1];
        float gg0 = (q0 * ka0.x + q1 * ka0.y + q2 * ka0.z) * RS3L; gg0 = e0 ? gg0 : -1e30f;
        float gg1 = (q0 * ka1.x + q1 * ka1.y + q2 * ka1.z) * RS3L; gg1 = e1 ? gg1 : -1e30f;
        float mx = fmaxf(gg0, gg1);
        for (u32 i = i0 + 64; i < end; i += 32) {
            float4 ka = p.kv2[p.ssorted[i] * 2];
            mx = fmaxf(mx, (q0 * ka.x + q1 * ka.y + q2 * ka.z) * RS3L);
        }
        #pragma unroll
        for (int o = 1; o < 32; o <<= 1) mx = fmaxf(mx, __shfl_xor(mx, o));
        float w0 = exp2f(gg0 - mx), w1 = exp2f(gg1 - mx);
        float sz = w0 + w1;
        float s0 = w0 * ka0.w + w1 * ka1.w;
        float s1 = w0 * kb0.x + w1 * kb1.x;
        float s2 = w0 * kb0.y + w1 * kb1.y;
        for (u32 i = i0 + 64; i < end; i += 32) {
            int s = p.ssorted[i];
            float4 ka = p.kv2[s * 2], kb = p.kv2[s * 2 + 1];
            float g = (q0 * ka.x + q1 * ka.y + q2 * ka.z) * RS3L;
            float w = exp2f(g - mx);
            sz += w; s0 += w * ka.w; s1 += w * kb.x; s2 += w * kb.y;
        }
        #pragma unroll
        for (int o = 1; o < 32; o <<= 1) {
            sz += __shfl_xor(sz, o);
            s0 += __shfl_xor(s0, o);
            s1 += __shfl_xor(s1, o);
            s2 += __shfl_xor(s2, o);
        }
        if (lane == 0) {
            float z = sz + 1e-16f;
            float h0 = p.h2[d * 3 + 0], h1 = p.h2[d * 3 + 1], h2 = p.h2[d * 3 + 2];
            float agg[3] = {s0 / z, s1 / z, s2 / z};
            #pragma unroll
            for (int c = 0; c < 3; ++c) {
                p.h3[d * 3 + c] = agg[c] + p.bsk[c] +
                    h0 * p.Wsk[c] + h1 * p.Wsk[3 + c] + h2 * p.Wsk[6 + c];
            }
        }
    }
    grid.sync();

    // ---- phase 9: MLP stage 1 (blocks 0..71) ----
    if (b < 72) {
        int t = gid;
        int j = t & 15;
        int g = t >> 4;             // 0..1151
        float acc = 0.f;
        #pragma unroll
        for (int k = 0; k < 16; ++k) {
            int r = g + k * 1152;
            acc += p.h3[r] * p.W1[r * 16 + j];
        }
        acc += __shfl_xor(acc, 16);
        acc += __shfl_xor(acc, 32);
        if ((tid & 63) < 16) red[(tid >> 6) * 16 + j] = acc;
        __syncthreads();
        if (tid < 16) {
            float s = red[tid] + red[16 + tid] + red[32 + tid] + red[48 + tid];
            atomicAdd(&p.a1pre[tid], s);
        }
    }
    grid.sync();

    // ---- phase 10: MLP stage 2 (block 0) ----
    if (b == 0) {
        if (tid < 16) a1s[tid] = fmaxf(p.a1pre[tid] + p.b1[tid], 0.f);
        __syncthreads();
        if (tid < 32) {
            float acc = p.b2[tid];
            #pragma unroll
            for (int i = 0; i < 16; ++i) acc += a1s[i] * p.W2[i * 32 + tid];
            p.a2buf[tid] = fmaxf(acc, 0.f);
        }
    }
    grid.sync();

    // ---- phase 11: MLP stage 3 (blocks 0..23) ----
    if (b < 24) {
        if (tid < 32) a2s[tid] = p.a2buf[tid];
        __syncthreads();
        int n = gid;
        float acc = p.b3[n];
        #pragma unroll
        for (int j = 0; j < 32; ++j) acc += a2s[j] * p.W3[(size_t)j * N + n];
        p.out[n] = acc * p.mask[n];
        float s = acc;
        #pragma unroll
        for (int o = 32; o; o >>= 1) s += __shfl_xor(s, o);
        if ((tid & 63) == 0) atomicAdd(p.sumres, s);
    }
    grid.sync();

    // ---- phase 12: value ----
    if (gid == 0) p.out[N] = p.cW[0] * (p.sumres[0] / (float)N) + p.cb[0];
}

// ===========================================================================
// Fallback path: round-7 multi-kernel pipeline (identical math).
// ===========================================================================
__global__ void k_hist(P p) {
    int e = blockIdx.x * 256 + threadIdx.x;
    if (e < N) {
        float h0 = p.x[e * 3 + 0], h1 = p.x[e * 3 + 1], h2 = p.x[e * 3 + 2];
        const float* W = p.gat_W;
        float xp0 = h0 * W[0] + h1 * W[3] + h2 * W[6];
        float xp1 = h0 * W[1] + h1 * W[4] + h2 * W[7];
        float xp2 = h0 * W[2] + h1 * W[5] + h2 * W[8];
        float ss = LOG2E * (xp0 * p.gat_asrc[0] + xp1 * p.gat_asrc[1] + xp2 * p.gat_asrc[2]);
        p.nodeA[e] = make_float4(xp0, xp1, xp2, ss);
        p.sdstA[e] = LOG2E * (xp0 * p.gat_adst[0] + xp1 * p.gat_adst[1] + xp2 * p.gat_adst[2]);
    }
    if (e >= EN) return;
    int d = (e < E) ? p.dst[e] : (e - E);
    atomicAdd(&p.deg[d], 1u);
}

__global__ void k_scan(P p) {
    __shared__ u32 part[256];
    int t = threadIdx.x;
    if (t < 3) p.kmaxk[t] = 0u;
    else if (t < 6) p.kmink[t - 3] = 0xFFFFFFFFu;
    else if (t < 22) p.a1pre[t - 6] = 0.f;
    else if (t == 22) p.sumres[0] = 0.f;
    u32 loc[24];
    u32 sum = 0;
    #pragma unroll
    for (int i = 0; i < 24; ++i) { loc[i] = sum; sum += p.deg[t * 24 + i]; }
    part[t] = sum;
    __syncthreads();
    for (int o = 1; o < 256; o <<= 1) {
        u32 v = (t >= o) ? part[t - o] : 0u;
        __syncthreads();
        part[t] += v;
        __syncthreads();
    }
    u32 base = (t == 0) ? 0u : part[t - 1];
    #pragma unroll
    for (int i = 0; i < 24; ++i) {
        u32 off = base + loc[i];
        p.offs[t * 24 + i] = off;
        p.cursor[t * 24 + i] = off;
    }
    if (t == 255) p.offs[N] = part[255];
}

__global__ void k_scatter(P p) {
    int e = blockIdx.x * 256 + threadIdx.x;
    if (e >= EN) return;
    int s = (e < E) ? p.src[e] : (e - E);
    int d = (e < E) ? p.dst[e] : (e - E);
    u32 pos = atomicAdd(&p.cursor[d], 1u);
    p.ssorted[pos] = s;
}

__global__ void k_gat_edge(P p, const float4* __restrict__ nin,
                           const float* __restrict__ sdin,
                           float4* __restrict__ nout, float* __restrict__ sdout,
                           int l) {
    int gid = blockIdx.x * 256 + threadIdx.x;
    int d = gid >> 5;
    int lane = gid & 31;
    u32 beg = p.offs[d], end = p.offs[d + 1];
    float sd = sdin[d];
    u32 i0 = beg + lane, i1 = i0 + 32, i2 = i0 + 64, i3 = i0 + 96;
    bool e0 = i0 < end, e1 = i1 < end, e2 = i2 < end, e3 = i3 < end;
    int j0 = e0 ? p.ssorted[i0] : 0;
    int j1 = e1 ? p.ssorted[i1] : 0;
    int j2 = e2 ? p.ssorted[i2] : 0;
    int j3 = e3 ? p.ssorted[i3] : 0;
    float4 r0 = nin[j0], r1 = nin[j1], r2 = nin[j2], r3 = nin[j3];
    float v0 = r0.w + sd; v0 = (v0 >= 0.f) ? v0 : 0.2f * v0; v0 = e0 ? v0 : -1e30f;
    float v1 = r1.w + sd; v1 = (v1 >= 0.f) ? v1 : 0.2f * v1; v1 = e1 ? v1 : -1e30f;
    float v2 = r2.w + sd; v2 = (v2 >= 0.f) ? v2 : 0.2f * v2; v2 = e2 ? v2 : -1e30f;
    float v3 = r3.w + sd; v3 = (v3 >= 0.f) ? v3 : 0.2f * v3; v3 = e3 ? v3 : -1e30f;
    float mx = fmaxf(fmaxf(v0, v1), fmaxf(v2, v3));
    for (u32 i = i0 + 128; i < end; i += 32) {
        float4 r = nin[p.ssorted[i]];
        float v = r.w + sd; v = (v >= 0.f) ? v : 0.2f * v;
        mx = fmaxf(mx, v);
    }
    #pragma unroll
    for (int o = 1; o < 32; o <<= 1) mx = fmaxf(mx, __shfl_xor(mx, o));
    float w0 = exp2f(v0 - mx), w1 = exp2f(v1 - mx),
          w2 = exp2f(v2 - mx), w3 = exp2f(v3 - mx);
    float sz = w0 + w1 + w2 + w3;
    float s0 = w0 * r0.x + w1 * r1.x + w2 * r2.x + w3 * r3.x;
    float s1 = w0 * r0.y + w1 * r1.y + w2 * r2.y + w3 * r3.y;
    float s2 = w0 * r0.z + w1 * r1.z + w2 * r2.z + w3 * r3.z;
    for (u32 i = i0 + 128; i < end; i += 32) {
        float4 r = nin[p.ssorted[i]];
        float v = r.w + sd; v = (v >= 0.f) ? v : 0.2f * v;
        float w = exp2f(v - mx);
        sz += w; s0 += w * r.x; s1 += w * r.y; s2 += w * r.z;
    }
    #pragma unroll
    for (int o = 1; o < 32; o <<= 1) {
        sz += __shfl_xor(sz, o);
        s0 += __shfl_xor(s0, o);
        s1 += __shfl_xor(s1, o);
        s2 += __shfl_xor(s2, o);
    }
    if (lane == 0) {
        float z = sz + 1e-16f;
        float o0 = s0 / z + p.gat_b[l * 3 + 0];
        float o1 = s1 / z + p.gat_b[l * 3 + 1];
        float o2 = s2 / z + p.gat_b[l * 3 + 2];
        if (l < LGAT - 1) {
            o0 = fmaxf(o0, 0.f); o1 = fmaxf(o1, 0.f); o2 = fmaxf(o2, 0.f);
            const float* W = p.gat_W + (l + 1) * 9;
            float xp0 = o0 * W[0] + o1 * W[3] + o2 * W[6];
            float xp1 = o0 * W[1] + o1 * W[4] + o2 * W[7];
            float xp2 = o0 * W[2] + o1 * W[5] + o2 * W[8];
            const float* as = p.gat_asrc + (l + 1) * 3;
            const float* ad = p.gat_adst + (l + 1) * 3;
            float ss = LOG2E * (xp0 * as[0] + xp1 * as[1] + xp2 * as[2]);
            nout[d] = make_float4(xp0, xp1, xp2, ss);
            sdout[d] = LOG2E * (xp0 * ad[0] + xp1 * ad[1] + xp2 * ad[2]);
        } else {
            float pr[9];
            #pragma unroll
            for (int j = 0; j < 9; ++j)
                pr[j] = o0 * p.in_w[j * 3 + 0] + o1 * p.in_w[j * 3 + 1] +
                        o2 * p.in_w[j * 3 + 2] + p.in_b[j];
            p.q3[d * 3 + 0] = pr[0]; p.q3[d * 3 + 1] = pr[1]; p.q3[d * 3 + 2] = pr[2];
            p.kvpack4[d * 2 + 0] = make_float4(pr[3], pr[4], pr[5], pr[6]);
            p.kvpack4[d * 2 + 1] = make_float4(pr[7], pr[8], 0.f, 0.f);
        }
    }
}

__global__ void k_kminmax(P p) {
    int n = blockIdx.x * 256 + threadIdx.x;
    float4 a = p.kvpack4[n * 2];
    float kk[3] = {a.x, a.y, a.z};
    #pragma unroll
    for (int hh = 0; hh < 3; ++hh) {
        float mx = kk[hh], mn = kk[hh];
        #pragma unroll
        for (int o = 32; o; o >>= 1) {
            mx = fmaxf(mx, __shfl_xor(mx, o));
            mn = fminf(mn, __shfl_xor(mn, o));
        }
        if ((threadIdx.x & 63) == 0) {
            atomicMax(&p.kmaxk[hh], f2key(mx));
            atomicMin(&p.kmink[hh], f2key(mn));
        }
    }
}

__global__ void k_att_partial(P p) {
    __shared__ float4 kv4[MCH * 2];
    int tid = threadIdx.x;
    int chunk = blockIdx.y;
    for (int i = tid; i < MCH * 2; i += 256) kv4[i] = p.kvpack4[chunk * MCH * 2 + i];
    __syncthreads();
    int n = blockIdx.x * 256 + tid;
    float q0 = p.q3[n * 3 + 0], q1 = p.q3[n * 3 + 1], q2 = p.q3[n * 3 + 2];
    float kmx0 = key2f(p.kmaxk[0]), kmx1 = key2f(p.kmaxk[1]), kmx2 = key2f(p.kmaxk[2]);
    float kmn0 = key2f(p.kmink[0]), kmn1 = key2f(p.kmink[1]), kmn2 = key2f(p.kmink[2]);
    float q0s = q0 * LOG2E, q1s = q1 * LOG2E, q2s = q2 * LOG2E;
    float nM0 = -((q0 >= 0.f) ? q0s * kmx0 : q0s * kmn0);
    float nM1 = -((q1 >= 0.f) ? q1s * kmx1 : q1s * kmn1);
    float nM2 = -((q2 >= 0.f) ? q2s * kmx2 : q2s * kmn2);
    float num0 = 0, den0 = 0, num1 = 0, den1 = 0, num2 = 0, den2 = 0;
    #pragma unroll 2
    for (int mm = 0; mm < MCH; ++mm) {
        float4 a = kv4[mm * 2], bb = kv4[mm * 2 + 1];
        float t0 = exp2f(fmaf(q0s, a.x, nM0)); den0 += t0; num0 = fmaf(t0, a.w, num0);
        float t1 = exp2f(fmaf(q1s, a.y, nM1)); den1 += t1; num1 = fmaf(t1, bb.x, num1);
        float t2 = exp2f(fmaf(q2s, a.z, nM2)); den2 += t2; num2 = fmaf(t2, bb.y, num2);
    }
    float* pp = p.part + (size_t)chunk * 6 * N + n;
    pp[0] = num0; pp[N] = den0; pp[2 * N] = num1;
    pp[3 * N] = den1; pp[4 * N] = num2; pp[5 * N] = den2;
}

__global__ void k_att_reduce(P p) {
    int n = blockIdx.x * 256 + threadIdx.x;
    float num[3] = {0.f, 0.f, 0.f}, den[3] = {0.f, 0.f, 0.f};
    for (int c = 0; c < 32; ++c) {
        const float* pp = p.part + (size_t)c * 6 * N + n;
        #pragma unroll
        for (int hh = 0; hh < 3; ++hh) {
            num[hh] += pp[hh * 2 * N];
            den[hh] += pp[(hh * 2 + 1) * N];
        }
    }
    float o[3];
    #pragma unroll
    for (int hh = 0; hh < 3; ++hh) o[hh] = num[hh] / den[hh];
    float h2v[3];
    #pragma unroll
    for (int c = 0; c < 3; ++c) {
        h2v[c] = p.out_b[c] + o[0] * p.out_w[c * 3 + 0] +
                 o[1] * p.out_w[c * 3 + 1] + o[2] * p.out_w[c * 3 + 2];
        p.h2[n * 3 + c] = h2v[c];
    }
    float q2v[3], k2v[3], v2v[3];
    #pragma unroll
    for (int c = 0; c < 3; ++c) {
        q2v[c] = p.bq[c] + h2v[0] * p.Wq[c] + h2v[1] * p.Wq[3 + c] + h2v[2] * p.Wq[6 + c];
        k2v[c] = p.bk[c] + h2v[0] * p.Wk[c] + h2v[1] * p.Wk[3 + c] + h2v[2] * p.Wk[6 + c];
        v2v[c] = p.bv[c] + h2v[0] * p.Wv[c] + h2v[1] * p.Wv[3 + c] + h2v[2] * p.Wv[6 + c];
        p.q2[n * 3 + c] = q2v[c];
    }
    p.kv2[n * 2 + 0] = make_float4(k2v[0], k2v[1], k2v[2], v2v[0]);
    p.kv2[n * 2 + 1] = make_float4(v2v[1], v2v[2], 0.f, 0.f);
}

__global__ void k_tc_edge(P p) {
    int gid = blockIdx.x * 256 + threadIdx.x;
    int d = gid >> 5;
    int lane = gid & 31;
    u32 beg = p.offs[d], end = p.offs[d + 1];
    float q0 = p.q2[d * 3 + 0], q1 = p.q2[d * 3 + 1], q2 = p.q2[d * 3 + 2];
    const float RS3L = 0.57735026919f * LOG2E;
    u32 i0 = beg + lane, i1 = i0 + 32;
    bool e0 = i0 < end, e1 = i1 < end;
    int j0 = e0 ? p.ssorted[i0] : 0;
    int j1 = e1 ? p.ssorted[i1] : 0;
    float4 ka0 = p.kv2[j0 * 2], kb0 = p.kv2[j0 * 2 + 1];
    float4 ka1 = p.kv2[j1 * 2], kb1 = p.kv2[j1 * 2 + 1];
    float g0 = (q0 * ka0.x + q1 * ka0.y + q2 * ka0.z) * RS3L; g0 = e0 ? g0 : -1e30f;
    float g1 = (q0 * ka1.x + q1 * ka1.y + q2 * ka1.z) * RS3L; g1 = e1 ? g1 : -1e30f;
    float mx = fmaxf(g0, g1);
    for (u32 i = i0 + 64; i < end; i += 32) {
        float4 ka = p.kv2[p.ssorted[i] * 2];
        mx = fmaxf(mx, (q0 * ka.x + q1 * ka.y + q2 * ka.z) * RS3L);
    }
    #pragma unroll
    for (int o = 1; o < 32; o <<= 1) mx = fmaxf(mx, __shfl_xor(mx, o));
    float w0 = exp2f(g0 - mx), w1 = exp2f(g1 - mx);
    float sz = w0 + w1;
    float s0 = w0 * ka0.w + w1 * ka1.w;
    float s1 = w0 * kb0.x + w1 * kb1.x;
    float s2 = w0 * kb0.y + w1 * kb1.y;
    for (u32 i = i0 + 64; i < end; i += 32) {
        int s = p.ssorted[i];
        float4 ka = p.kv2[s * 2], kb = p.kv2[s * 2 + 1];
        float g = (q0 * ka.x + q1 * ka.y + q2 * ka.z) * RS3L;
        float w = exp2f(g - mx);
        sz += w; s0 += w * ka.w; s1 += w * kb.x; s2 += w * kb.y;
    }
    #pragma unroll
    for (int o = 1; o < 32; o <<= 1) {
        sz += __shfl_xor(sz, o);
        s0 += __shfl_xor(s0, o);
        s1 += __shfl_xor(s1, o);
        s2 += __shfl_xor(s2, o);
    }
    if (lane == 0) {
        float z = sz + 1e-16f;
        float h0 = p.h2[d * 3 + 0], h1 = p.h2[d * 3 + 1], h2 = p.h2[d * 3 + 2];
        float agg[3] = {s0 / z, s1 / z, s2 / z};
        #pragma unroll
        for (int c = 0; c < 3; ++c) {
            p.h3[d * 3 + c] = agg[c] + p.bsk[c] +
                h0 * p.Wsk[c] + h1 * p.Wsk[3 + c] + h2 * p.Wsk[6 + c];
        }
    }
}

__global__ void k_mlp1(P p) {
    __shared__ float red[64];
    int t = blockIdx.x * 256 + threadIdx.x;
    int j = t & 15;
    int g = t >> 4;
    float acc = 0.f;
    #pragma unroll
    for (int k = 0; k < 16; ++k) {
        int r = g + k * 1152;
        acc += p.h3[r] * p.W1[r * 16 + j];
    }
    acc += __shfl_xor(acc, 16);
    acc += __shfl_xor(acc, 32);
    int tid = threadIdx.x;
    if ((tid & 63) < 16) red[(tid >> 6) * 16 + j] = acc;
    __syncthreads();
    if (tid < 16) {
        float s = red[tid] + red[16 + tid] + red[32 + tid] + red[48 + tid];
        atomicAdd(&p.a1pre[tid], s);
    }
}

__global__ void k_mlp2(P p) {
    __shared__ float a1[16];
    int t = threadIdx.x;
    if (t < 16) a1[t] = fmaxf(p.a1pre[t] + p.b1[t], 0.f);
    __syncthreads();
    if (t < 32) {
        float acc = p.b2[t];
        #pragma unroll
        for (int i = 0; i < 16; ++i) acc += a1[i] * p.W2[i * 32 + t];
        p.a2buf[t] = fmaxf(acc, 0.f);
    }
}

__global__ void k_mlp3(P p) {
    __shared__ float a2[32];
    if (threadIdx.x < 32) a2[threadIdx.x] = p.a2buf[threadIdx.x];
    __syncthreads();
    int n = blockIdx.x * 256 + threadIdx.x;
    float acc = p.b3[n];
    #pragma unroll
    for (int j = 0; j < 32; ++j) acc += a2[j] * p.W3[(size_t)j * N + n];
    p.out[n] = acc * p.mask[n];
    float s = acc;
    #pragma unroll
    for (int o = 32; o; o >>= 1) s += __shfl_xor(s, o);
    if ((threadIdx.x & 63) == 0) atomicAdd(p.sumres, s);
}

__global__ void k_value(P p) {
    p.out[N] = p.cW[0] * (p.sumres[0] / (float)N) + p.cb[0];
}

extern "C" void kernel_launch(void* const* d_in, const int* in_sizes, int n_in,
                              void* d_out, int out_size, void* d_ws, size_t ws_size,
                              hipStream_t stream) {
    P p;
    p.x      = (const float*)d_in[0];
    p.mask   = (const float*)d_in[1];
    const int* ei = (const int*)d_in[2];
    p.src = ei; p.dst = ei + E;
    p.gat_W  = (const float*)d_in[3];
    p.gat_asrc = (const float*)d_in[4];
    p.gat_adst = (const float*)d_in[5];
    p.gat_b  = (const float*)d_in[6];
    p.in_w   = (const float*)d_in[7];
    p.in_b   = (const float*)d_in[8];
    p.out_w  = (const float*)d_in[9];
    p.out_b  = (const float*)d_in[10];
    p.Wq = (const float*)d_in[11]; p.bq = (const float*)d_in[12];
    p.Wk = (const float*)d_in[13]; p.bk = (const float*)d_in[14];
    p.Wv = (const float*)d_in[15]; p.bv = (const float*)d_in[16];
    p.Wsk = (const float*)d_in[17]; p.bsk = (const float*)d_in[18];
    p.W1 = (const float*)d_in[19]; p.b1 = (const float*)d_in[20];
    p.W2 = (const float*)d_in[21]; p.b2 = (const float*)d_in[22];
    p.W3 = (const float*)d_in[23]; p.b3 = (const float*)d_in[24];
    p.cW = (const float*)d_in[25]; p.cb = (const float*)d_in[26];

    float* ws = (float*)d_ws;
    p.nodeA   = (float4*)(ws + 0);       // 24576 floats
    p.nodeB   = (float4*)(ws + 24576);   // 24576
    p.sdstA   = ws + 49152;              // 6144
    p.sdstB   = ws + 55296;              // 6144
    p.q3      = ws + 61440;              // 18432
    p.kvpack4 = (float4*)(ws + 79872);   // 49152 floats
    p.q2      = ws + 129024;             // 18432
    p.kv2     = (float4*)(ws + 147456);  // 49152
    p.h2      = ws + 196608;             // 18432
    p.h3      = ws + 215040;             // 18432
    p.part    = ws + 233472;             // 1179648
    p.a1pre   = ws + 1413120;            // 16
    p.a2buf   = ws + 1413136;            // 32
    p.sumres  = ws + 1413168;            // 1
    p.kmaxk   = (u32*)(ws + 1413172);    // 3
    p.kmink   = (u32*)(ws + 1413175);    // 3
    p.deg     = (u32*)(ws + 1413178);    // 6144
    p.offs    = (u32*)(ws + 1419322);    // 6145
    p.cursor  = (u32*)(ws + 1425467);    // 6144
    p.ssorted = (int*)(ws + 1431611);    // 202752
    p.out     = (float*)d_out;

    // -- decide cooperative vs fallback via host-only queries (capture-safe) --
    int coopOK = 0, numCU = 0, maxPerCU = 0;
    hipDeviceGetAttribute(&coopOK, hipDeviceAttributeCooperativeLaunch, 0);
    hipDeviceGetAttribute(&numCU, hipDeviceAttributeMultiprocessorCount, 0);
    hipOccupancyMaxActiveBlocksPerMultiprocessor(&maxPerCU, k_mega, 256, 0);
    int nb = maxPerCU * numCU;
    if (nb > 768) nb = 768;

    bool done = false;
    if (coopOK && nb >= 72) {
        void* args[] = { (void*)&p };
        if (hipLaunchCooperativeKernel((const void*)k_mega, dim3(nb), dim3(256),
                                       args, 0, stream) == hipSuccess)
            done = true;
    }
    if (!done) {
        // deterministic multi-kernel fallback (round-7 path, identical math)
        hipMemsetAsync(p.deg, 0, N * sizeof(u32), stream);
        k_hist<<<792, 256, 0, stream>>>(p);
        k_scan<<<1, 256, 0, stream>>>(p);
        k_scatter<<<792, 256, 0, stream>>>(p);
        for (int l = 0; l < LGAT; ++l) {
            const float4* nin = (l & 1) ? p.nodeB : p.nodeA;
            const float*  sdin = (l & 1) ? p.sdstB : p.sdstA;
            float4* nout = (l & 1) ? p.nodeA : p.nodeB;
            float*  sdout = (l & 1) ? p.sdstA : p.sdstB;
            k_gat_edge<<<768, 256, 0, stream>>>(p, nin, sdin, nout, sdout, l);
        }
        k_kminmax<<<24, 256, 0, stream>>>(p);
        k_att_partial<<<dim3(24, 32), 256, 0, stream>>>(p);
        k_att_reduce<<<24, 256, 0, stream>>>(p);
        k_tc_edge<<<768, 256, 0, stream>>>(p);
        k_mlp1<<<72, 256, 0, stream>>>(p);
        k_mlp2<<<1, 64, 0, stream>>>(p);
        k_mlp3<<<24, 256, 0, stream>>>(p);
        k_value<<<1, 1, 0, stream>>>(p);
    }
}

// Round 10
// 254.162 us; speedup vs baseline: 3.3896x; 3.3896x over previous
//
#include <hip/hip_runtime.h>

#define N 6144
#define E 196608
#define EN (E + N)      // 202752
#define LGAT 10
#define LOG2E 1.4426950408889634f
#define MCH 192   // 6144/32

typedef unsigned int u32;

// order-preserving float<->uint for atomicMax/Min on floats (incl. negatives)
__device__ __forceinline__ u32 f2key(float f) {
    u32 u = __float_as_uint(f);
    return (u & 0x80000000u) ? ~u : (u | 0x80000000u);
}
__device__ __forceinline__ float key2f(u32 k) {
    u32 u = (k & 0x80000000u) ? (k & 0x7FFFFFFFu) : ~k;
    return __uint_as_float(u);
}

struct P {
    // fp32 inputs
    const float *x, *mask, *gat_W, *gat_asrc, *gat_adst, *gat_b;
    const float *in_w, *in_b, *out_w, *out_b;
    const float *Wq, *bq, *Wk, *bk, *Wv, *bv, *Wsk, *bsk;
    const float *W1, *b1, *W2, *b2, *W3, *b3, *cW, *cb;
    const int *src, *dst;
    // fp32 workspace
    float4 *nodeA, *nodeB;          // per-node {xp0,xp1,xp2,ssrc*log2e}
    float *sdstA, *sdstB;           // sdst*log2e
    float *q3, *q2, *h2, *h3, *part;
    float4 *kvpack4;                // per-node {k0,k1,k2,v0},{v1,v2,0,0}
    float4 *kv2;                    // per-node {k0,k1,k2,v0},{v1,v2,0,0} (TC)
    float *a1pre, *a2buf, *sumres;
    u32 *deg, *offs, *cursor, *kmaxk, *kmink, *m1ct, *m3ct;
    int *ssorted;
    float *out;
};

// ---- CSR pass 1 (histogram of dst) + fused layer-0 node transform --------
__global__ void k_hist(P p) {
    int e = blockIdx.x * 256 + threadIdx.x;
    if (e < N) {
        float h0 = p.x[e * 3 + 0], h1 = p.x[e * 3 + 1], h2 = p.x[e * 3 + 2];
        const float* W = p.gat_W;
        float xp0 = h0 * W[0] + h1 * W[3] + h2 * W[6];
        float xp1 = h0 * W[1] + h1 * W[4] + h2 * W[7];
        float xp2 = h0 * W[2] + h1 * W[5] + h2 * W[8];
        float ss = LOG2E * (xp0 * p.gat_asrc[0] + xp1 * p.gat_asrc[1] + xp2 * p.gat_asrc[2]);
        p.nodeA[e] = make_float4(xp0, xp1, xp2, ss);
        p.sdstA[e] = LOG2E * (xp0 * p.gat_adst[0] + xp1 * p.gat_adst[1] + xp2 * p.gat_adst[2]);
    }
    if (e >= EN) return;
    int d = (e < E) ? p.dst[e] : (e - E);
    atomicAdd(&p.deg[d], 1u);
}

// ---- CSR pass 2: exclusive scan (single block) + tiny inits --------------
__global__ void k_scan(P p) {
    __shared__ u32 part[256];
    int t = threadIdx.x;
    if (t < 3) p.kmaxk[t] = 0u;
    else if (t < 6) p.kmink[t - 3] = 0xFFFFFFFFu;
    else if (t < 22) p.a1pre[t - 6] = 0.f;
    else if (t == 22) p.sumres[0] = 0.f;
    else if (t == 23) p.m1ct[0] = 0u;
    else if (t == 24) p.m3ct[0] = 0u;
    u32 loc[24];
    u32 sum = 0;
    #pragma unroll
    for (int i = 0; i < 24; ++i) { loc[i] = sum; sum += p.deg[t * 24 + i]; }
    part[t] = sum;
    __syncthreads();
    for (int o = 1; o < 256; o <<= 1) {
        u32 v = (t >= o) ? part[t - o] : 0u;
        __syncthreads();
        part[t] += v;
        __syncthreads();
    }
    u32 base = (t == 0) ? 0u : part[t - 1];
    #pragma unroll
    for (int i = 0; i < 24; ++i) {
        u32 off = base + loc[i];
        p.offs[t * 24 + i] = off;
        p.cursor[t * 24 + i] = off;
    }
    if (t == 255) p.offs[N] = part[255];
}

// ---- CSR pass 3: scatter src ids into dst-sorted order -------------------
__global__ void k_scatter(P p) {
    int e = blockIdx.x * 256 + threadIdx.x;
    if (e >= EN) return;
    int s = (e < E) ? p.src[e] : (e - E);
    int d = (e < E) ? p.dst[e] : (e - E);
    u32 pos = atomicAdd(&p.cursor[d], 1u);
    p.ssorted[pos] = s;
}

// ---- GAT edge kernel: 32 lanes/dst, single gather (register-cached) ------
__global__ void k_gat_edge(P p, const float4* __restrict__ nin,
                           const float* __restrict__ sdin,
                           float4* __restrict__ nout, float* __restrict__ sdout,
                           int l) {
    int gid = blockIdx.x * 256 + threadIdx.x;
    int d = gid >> 5;
    int lane = gid & 31;
    u32 beg = p.offs[d], end = p.offs[d + 1];
    float sd = sdin[d];
    u32 i0 = beg + lane, i1 = i0 + 32, i2 = i0 + 64, i3 = i0 + 96;
    bool e0 = i0 < end, e1 = i1 < end, e2 = i2 < end, e3 = i3 < end;
    int j0 = e0 ? p.ssorted[i0] : 0;
    int j1 = e1 ? p.ssorted[i1] : 0;
    int j2 = e2 ? p.ssorted[i2] : 0;
    int j3 = e3 ? p.ssorted[i3] : 0;
    float4 r0 = nin[j0], r1 = nin[j1], r2 = nin[j2], r3 = nin[j3];
    float v0 = r0.w + sd; v0 = (v0 >= 0.f) ? v0 : 0.2f * v0; v0 = e0 ? v0 : -1e30f;
    float v1 = r1.w + sd; v1 = (v1 >= 0.f) ? v1 : 0.2f * v1; v1 = e1 ? v1 : -1e30f;
    float v2 = r2.w + sd; v2 = (v2 >= 0.f) ? v2 : 0.2f * v2; v2 = e2 ? v2 : -1e30f;
    float v3 = r3.w + sd; v3 = (v3 >= 0.f) ? v3 : 0.2f * v3; v3 = e3 ? v3 : -1e30f;
    float mx = fmaxf(fmaxf(v0, v1), fmaxf(v2, v3));
    for (u32 i = i0 + 128; i < end; i += 32) {
        float4 r = nin[p.ssorted[i]];
        float v = r.w + sd; v = (v >= 0.f) ? v : 0.2f * v;
        mx = fmaxf(mx, v);
    }
    #pragma unroll
    for (int o = 1; o < 32; o <<= 1) mx = fmaxf(mx, __shfl_xor(mx, o));
    float w0 = exp2f(v0 - mx), w1 = exp2f(v1 - mx),
          w2 = exp2f(v2 - mx), w3 = exp2f(v3 - mx);
    float sz = w0 + w1 + w2 + w3;
    float s0 = w0 * r0.x + w1 * r1.x + w2 * r2.x + w3 * r3.x;
    float s1 = w0 * r0.y + w1 * r1.y + w2 * r2.y + w3 * r3.y;
    float s2 = w0 * r0.z + w1 * r1.z + w2 * r2.z + w3 * r3.z;
    for (u32 i = i0 + 128; i < end; i += 32) {
        float4 r = nin[p.ssorted[i]];
        float v = r.w + sd; v = (v >= 0.f) ? v : 0.2f * v;
        float w = exp2f(v - mx);
        sz += w; s0 += w * r.x; s1 += w * r.y; s2 += w * r.z;
    }
    #pragma unroll
    for (int o = 1; o < 32; o <<= 1) {
        sz += __shfl_xor(sz, o);
        s0 += __shfl_xor(s0, o);
        s1 += __shfl_xor(s1, o);
        s2 += __shfl_xor(s2, o);
    }
    if (lane == 0) {
        float z = sz + 1e-16f;
        float o0 = s0 / z + p.gat_b[l * 3 + 0];
        float o1 = s1 / z + p.gat_b[l * 3 + 1];
        float o2 = s2 / z + p.gat_b[l * 3 + 2];
        if (l < LGAT - 1) {
            o0 = fmaxf(o0, 0.f); o1 = fmaxf(o1, 0.f); o2 = fmaxf(o2, 0.f);
            const float* W = p.gat_W + (l + 1) * 9;
            float xp0 = o0 * W[0] + o1 * W[3] + o2 * W[6];
            float xp1 = o0 * W[1] + o1 * W[4] + o2 * W[7];
            float xp2 = o0 * W[2] + o1 * W[5] + o2 * W[8];
            const float* as = p.gat_asrc + (l + 1) * 3;
            const float* ad = p.gat_adst + (l + 1) * 3;
            float ss = LOG2E * (xp0 * as[0] + xp1 * as[1] + xp2 * as[2]);
            nout[d] = make_float4(xp0, xp1, xp2, ss);
            sdout[d] = LOG2E * (xp0 * ad[0] + xp1 * ad[1] + xp2 * ad[2]);
        } else {
            float pr[9];
            #pragma unroll
            for (int j = 0; j < 9; ++j)
                pr[j] = o0 * p.in_w[j * 3 + 0] + o1 * p.in_w[j * 3 + 1] +
                        o2 * p.in_w[j * 3 + 2] + p.in_b[j];
            p.q3[d * 3 + 0] = pr[0]; p.q3[d * 3 + 1] = pr[1]; p.q3[d * 3 + 2] = pr[2];
            p.kvpack4[d * 2 + 0] = make_float4(pr[3], pr[4], pr[5], pr[6]);
            p.kvpack4[d * 2 + 1] = make_float4(pr[7], pr[8], 0.f, 0.f);
        }
    }
}

// ---- global k min/max per head (wave pre-reduced) ------------------------
__global__ void k_kminmax(P p) {
    int n = blockIdx.x * 256 + threadIdx.x;
    float4 a = p.kvpack4[n * 2];
    float kk[3] = {a.x, a.y, a.z};
    #pragma unroll
    for (int hh = 0; hh < 3; ++hh) {
        float mx = kk[hh], mn = kk[hh];
        #pragma unroll
        for (int o = 32; o; o >>= 1) {
            mx = fmaxf(mx, __shfl_xor(mx, o));
            mn = fminf(mn, __shfl_xor(mn, o));
        }
        if ((threadIdx.x & 63) == 0) {
            atomicMax(&p.kmaxk[hh], f2key(mx));
            atomicMin(&p.kmink[hh], f2key(mn));
        }
    }
}

// ---- MHA: rank-1 attention; LDS float4-packed kv, exp2 folding -----------
__global__ void k_att_partial(P p) {
    __shared__ float4 kv4[MCH * 2];
    int tid = threadIdx.x;
    int chunk = blockIdx.y;
    for (int i = tid; i < MCH * 2; i += 256) kv4[i] = p.kvpack4[chunk * MCH * 2 + i];
    __syncthreads();
    int n = blockIdx.x * 256 + tid;
    float q0 = p.q3[n * 3 + 0], q1 = p.q3[n * 3 + 1], q2 = p.q3[n * 3 + 2];
    float kmx0 = key2f(p.kmaxk[0]), kmx1 = key2f(p.kmaxk[1]), kmx2 = key2f(p.kmaxk[2]);
    float kmn0 = key2f(p.kmink[0]), kmn1 = key2f(p.kmink[1]), kmn2 = key2f(p.kmink[2]);
    float q0s = q0 * LOG2E, q1s = q1 * LOG2E, q2s = q2 * LOG2E;
    float nM0 = -((q0 >= 0.f) ? q0s * kmx0 : q0s * kmn0);
    float nM1 = -((q1 >= 0.f) ? q1s * kmx1 : q1s * kmn1);
    float nM2 = -((q2 >= 0.f) ? q2s * kmx2 : q2s * kmn2);
    float num0 = 0, den0 = 0, num1 = 0, den1 = 0, num2 = 0, den2 = 0;
    #pragma unroll 2
    for (int mm = 0; mm < MCH; ++mm) {
        float4 a = kv4[mm * 2], bb = kv4[mm * 2 + 1];
        float t0 = exp2f(fmaf(q0s, a.x, nM0)); den0 += t0; num0 = fmaf(t0, a.w, num0);
        float t1 = exp2f(fmaf(q1s, a.y, nM1)); den1 += t1; num1 = fmaf(t1, bb.x, num1);
        float t2 = exp2f(fmaf(q2s, a.z, nM2)); den2 += t2; num2 = fmaf(t2, bb.y, num2);
    }
    float* pp = p.part + (size_t)chunk * 6 * N + n;
    pp[0] = num0; pp[N] = den0; pp[2 * N] = num1;
    pp[3 * N] = den1; pp[4 * N] = num2; pp[5 * N] = den2;
}

// ---- MHA reduce + out-proj + TC q2/kv2 records ---------------------------
__global__ void k_att_reduce(P p) {
    int n = blockIdx.x * 256 + threadIdx.x;
    float num[3] = {0.f, 0.f, 0.f}, den[3] = {0.f, 0.f, 0.f};
    for (int c = 0; c < 32; ++c) {
        const float* pp = p.part + (size_t)c * 6 * N + n;
        #pragma unroll
        for (int hh = 0; hh < 3; ++hh) {
            num[hh] += pp[hh * 2 * N];
            den[hh] += pp[(hh * 2 + 1) * N];
        }
    }
    float o[3];
    #pragma unroll
    for (int hh = 0; hh < 3; ++hh) o[hh] = num[hh] / den[hh];
    float h2v[3];
    #pragma unroll
    for (int c = 0; c < 3; ++c) {
        h2v[c] = p.out_b[c] + o[0] * p.out_w[c * 3 + 0] +
                 o[1] * p.out_w[c * 3 + 1] + o[2] * p.out_w[c * 3 + 2];
        p.h2[n * 3 + c] = h2v[c];
    }
    float q2v[3], k2v[3], v2v[3];
    #pragma unroll
    for (int c = 0; c < 3; ++c) {
        q2v[c] = p.bq[c] + h2v[0] * p.Wq[c] + h2v[1] * p.Wq[3 + c] + h2v[2] * p.Wq[6 + c];
        k2v[c] = p.bk[c] + h2v[0] * p.Wk[c] + h2v[1] * p.Wk[3 + c] + h2v[2] * p.Wk[6 + c];
        v2v[c] = p.bv[c] + h2v[0] * p.Wv[c] + h2v[1] * p.Wv[3 + c] + h2v[2] * p.Wv[6 + c];
        p.q2[n * 3 + c] = q2v[c];
    }
    p.kv2[n * 2 + 0] = make_float4(k2v[0], k2v[1], k2v[2], v2v[0]);
    p.kv2[n * 2 + 1] = make_float4(v2v[1], v2v[2], 0.f, 0.f);
}

// ---- TC fused edge kernel: 32 lanes/dst, single gather -------------------
__global__ void k_tc_edge(P p) {
    int gid = blockIdx.x * 256 + threadIdx.x;
    int d = gid >> 5;
    int lane = gid & 31;
    u32 beg = p.offs[d], end = p.offs[d + 1];
    float q0 = p.q2[d * 3 + 0], q1 = p.q2[d * 3 + 1], q2 = p.q2[d * 3 + 2];
    const float RS3L = 0.57735026919f * LOG2E;
    u32 i0 = beg + lane, i1 = i0 + 32;
    bool e0 = i0 < end, e1 = i1 < end;
    int j0 = e0 ? p.ssorted[i0] : 0;
    int j1 = e1 ? p.ssorted[i1] : 0;
    float4 ka0 = p.kv2[j0 * 2], kb0 = p.kv2[j0 * 2 + 1];
    float4 ka1 = p.kv2[j1 * 2], kb1 = p.kv2[j1 * 2 + 1];
    float g0 = (q0 * ka0.x + q1 * ka0.y + q2 * ka0.z) * RS3L; g0 = e0 ? g0 : -1e30f;
    float g1 = (q0 * ka1.x + q1 * ka1.y + q2 * ka1.z) * RS3L; g1 = e1 ? g1 : -1e30f;
    float mx = fmaxf(g0, g1);
    for (u32 i = i0 + 64; i < end; i += 32) {
        float4 ka = p.kv2[p.ssorted[i] * 2];
        mx = fmaxf(mx, (q0 * ka.x + q1 * ka.y + q2 * ka.z) * RS3L);
    }
    #pragma unroll
    for (int o = 1; o < 32; o <<= 1) mx = fmaxf(mx, __shfl_xor(mx, o));
    float w0 = exp2f(g0 - mx), w1 = exp2f(g1 - mx);
    float sz = w0 + w1;
    float s0 = w0 * ka0.w + w1 * ka1.w;
    float s1 = w0 * kb0.x + w1 * kb1.x;
    float s2 = w0 * kb0.y + w1 * kb1.y;
    for (u32 i = i0 + 64; i < end; i += 32) {
        int s = p.ssorted[i];
        float4 ka = p.kv2[s * 2], kb = p.kv2[s * 2 + 1];
        float g = (q0 * ka.x + q1 * ka.y + q2 * ka.z) * RS3L;
        float w = exp2f(g - mx);
        sz += w; s0 += w * ka.w; s1 += w * kb.x; s2 += w * kb.y;
    }
    #pragma unroll
    for (int o = 1; o < 32; o <<= 1) {
        sz += __shfl_xor(sz, o);
        s0 += __shfl_xor(s0, o);
        s1 += __shfl_xor(s1, o);
        s2 += __shfl_xor(s2, o);
    }
    if (lane == 0) {
        float z = sz + 1e-16f;
        float h0 = p.h2[d * 3 + 0], h1 = p.h2[d * 3 + 1], h2 = p.h2[d * 3 + 2];
        float agg[3] = {s0 / z, s1 / z, s2 / z};
        #pragma unroll
        for (int c = 0; c < 3; ++c) {
            p.h3[d * 3 + c] = agg[c] + p.bsk[c] +
                h0 * p.Wsk[c] + h1 * p.Wsk[3 + c] + h2 * p.Wsk[6 + c];
        }
    }
}

// ---- MLP stage 1 + fused stage 2 in last block (ticket pattern) ----------
// a1pre is accumulated with device-scope atomicAdd (coherent across XCDs);
// the last block re-reads it with agent-scope atomic loads -> safe.
__global__ void k_mlp1(P p) {
    __shared__ float red[64];
    __shared__ float a1s[16];
    __shared__ u32 tick;
    int t = blockIdx.x * 256 + threadIdx.x;
    int tid = threadIdx.x;
    int j = t & 15;
    int g = t >> 4;
    float acc = 0.f;
    #pragma unroll
    for (int k = 0; k < 16; ++k) {
        int r = g + k * 1152;
        acc += p.h3[r] * p.W1[r * 16 + j];
    }
    acc += __shfl_xor(acc, 16);
    acc += __shfl_xor(acc, 32);
    if ((tid & 63) < 16) red[(tid >> 6) * 16 + j] = acc;
    __syncthreads();
    if (tid < 16) {
        float s = red[tid] + red[16 + tid] + red[32 + tid] + red[48 + tid];
        atomicAdd(&p.a1pre[tid], s);
    }
    __syncthreads();
    if (tid == 0) {
        __threadfence();
        tick = __hip_atomic_fetch_add(p.m1ct, 1u, __ATOMIC_ACQ_REL, __HIP_MEMORY_SCOPE_AGENT);
    }
    __syncthreads();
    if (tick == 71) {   // last block: fused MLP stage 2
        if (tid < 16) {
            float v = __hip_atomic_load(&p.a1pre[tid], __ATOMIC_RELAXED, __HIP_MEMORY_SCOPE_AGENT);
            a1s[tid] = fmaxf(v + p.b1[tid], 0.f);
        }
        __syncthreads();
        if (tid < 32) {
            float acc2 = p.b2[tid];
            #pragma unroll
            for (int i = 0; i < 16; ++i) acc2 += a1s[i] * p.W2[i * 32 + tid];
            p.a2buf[tid] = fmaxf(acc2, 0.f);   // visible after kernel boundary
        }
    }
}

// ---- MLP stage 3 + fused value in last block -----------------------------
__global__ void k_mlp3(P p) {
    __shared__ float a2[32];
    __shared__ u32 tick;
    int tid = threadIdx.x;
    if (tid < 32) a2[tid] = p.a2buf[tid];
    __syncthreads();
    int n = blockIdx.x * 256 + tid;
    float acc = p.b3[n];
    #pragma unroll
    for (int j = 0; j < 32; ++j) acc += a2[j] * p.W3[(size_t)j * N + n];
    p.out[n] = acc * p.mask[n];
    float s = acc;
    #pragma unroll
    for (int o = 32; o; o >>= 1) s += __shfl_xor(s, o);
    if ((tid & 63) == 0) atomicAdd(p.sumres, s);
    __syncthreads();
    if (tid == 0) {
        __threadfence();
        tick = __hip_atomic_fetch_add(p.m3ct, 1u, __ATOMIC_ACQ_REL, __HIP_MEMORY_SCOPE_AGENT);
    }
    __syncthreads();
    if (tick == 23 && tid == 0) {   // last block: fused value epilogue
        float sr = __hip_atomic_load(p.sumres, __ATOMIC_RELAXED, __HIP_MEMORY_SCOPE_AGENT);
        p.out[N] = p.cW[0] * (sr / (float)N) + p.cb[0];
    }
}

extern "C" void kernel_launch(void* const* d_in, const int* in_sizes, int n_in,
                              void* d_out, int out_size, void* d_ws, size_t ws_size,
                              hipStream_t stream) {
    P p;
    p.x      = (const float*)d_in[0];
    p.mask   = (const float*)d_in[1];
    const int* ei = (const int*)d_in[2];
    p.src = ei; p.dst = ei + E;
    p.gat_W  = (const float*)d_in[3];
    p.gat_asrc = (const float*)d_in[4];
    p.gat_adst = (const float*)d_in[5];
    p.gat_b  = (const float*)d_in[6];
    p.in_w   = (const float*)d_in[7];
    p.in_b   = (const float*)d_in[8];
    p.out_w  = (const float*)d_in[9];
    p.out_b  = (const float*)d_in[10];
    p.Wq = (const float*)d_in[11]; p.bq = (const float*)d_in[12];
    p.Wk = (const float*)d_in[13]; p.bk = (const float*)d_in[14];
    p.Wv = (const float*)d_in[15]; p.bv = (const float*)d_in[16];
    p.Wsk = (const float*)d_in[17]; p.bsk = (const float*)d_in[18];
    p.W1 = (const float*)d_in[19]; p.b1 = (const float*)d_in[20];
    p.W2 = (const float*)d_in[21]; p.b2 = (const float*)d_in[22];
    p.W3 = (const float*)d_in[23]; p.b3 = (const float*)d_in[24];
    p.cW = (const float*)d_in[25]; p.cb = (const float*)d_in[26];

    float* ws = (float*)d_ws;
    p.nodeA   = (float4*)(ws + 0);       // 24576 floats
    p.nodeB   = (float4*)(ws + 24576);   // 24576
    p.sdstA   = ws + 49152;              // 6144
    p.sdstB   = ws + 55296;              // 6144
    p.q3      = ws + 61440;              // 18432
    p.kvpack4 = (float4*)(ws + 79872);   // 49152 floats
    p.q2      = ws + 129024;             // 18432
    p.kv2     = (float4*)(ws + 147456);  // 49152
    p.h2      = ws + 196608;             // 18432
    p.h3      = ws + 215040;             // 18432
    p.part    = ws + 233472;             // 1179648
    p.a1pre   = ws + 1413120;            // 16
    p.a2buf   = ws + 1413136;            // 32
    p.sumres  = ws + 1413168;            // 1
    p.kmaxk   = (u32*)(ws + 1413172);    // 3
    p.kmink   = (u32*)(ws + 1413175);    // 3
    p.m1ct    = (u32*)(ws + 1413178);    // 1
    p.m3ct    = (u32*)(ws + 1413179);    // 1
    p.deg     = (u32*)(ws + 1413180);    // 6144
    p.offs    = (u32*)(ws + 1419324);    // 6145
    p.cursor  = (u32*)(ws + 1425469);    // 6144
    p.ssorted = (int*)(ws + 1431613);    // 202752
    p.out     = (float*)d_out;

    // CSR build (once per launch); node0 fused into k_hist
    hipMemsetAsync(p.deg, 0, N * sizeof(u32), stream);
    k_hist<<<792, 256, 0, stream>>>(p);
    k_scan<<<1, 256, 0, stream>>>(p);
    k_scatter<<<792, 256, 0, stream>>>(p);
    // GAT stack: ping-pong node records, single-gather edge kernels
    for (int l = 0; l < LGAT; ++l) {
        const float4* nin = (l & 1) ? p.nodeB : p.nodeA;
        const float*  sdin = (l & 1) ? p.sdstB : p.sdstA;
        float4* nout = (l & 1) ? p.nodeA : p.nodeB;
        float*  sdout = (l & 1) ? p.sdstA : p.sdstB;
        k_gat_edge<<<768, 256, 0, stream>>>(p, nin, sdin, nout, sdout, l);
    }
    // MHA
    k_kminmax<<<24, 256, 0, stream>>>(p);
    k_att_partial<<<dim3(24, 32), 256, 0, stream>>>(p);
    k_att_reduce<<<24, 256, 0, stream>>>(p);
    // TC
    k_tc_edge<<<768, 256, 0, stream>>>(p);
    // MLP (stage 2 fused into stage 1's last block; value into stage 3's)
    k_mlp1<<<72, 256, 0, stream>>>(p);
    k_mlp3<<<24, 256, 0, stream>>>(p);
}